// Round 3
// baseline (88.571 us; speedup 1.0000x reference)
//
#include <hip/hip_runtime.h>
#include <math.h>

#define R 2048
#define C 1024
#define CH 8
#define K 64  // CH*BA

// Output layout (floats), reference return order:
#define OFF_P     0
#define OFF_TOT   (R*K)            // 131072
#define OFF_MAX   (OFF_TOT + 8)
#define OFF_NCOL  (OFF_MAX + 8)
#define OFF_NROW  (OFF_NCOL + 8)
#define OFF_NNZ   (OFF_NROW + 8)
#define OFF_DEN   (OFF_NNZ + 64)
#define OFF_SEL   (OFF_DEN + 8)

// ws layout (floats):
#define WS_LQ   0          // lq2[R][8]: clamped log2 of per-(row,ch) prod(1-p)
#define WS_COL  16384      // colacc[8][1024]: zeroed by k0, atomics in phase 2
#define WS_CNT  24576      // 64 per-rc arrival counters + [64] finale gate (uints)
#define WS_NP   24704      // nnzpart[256][64]
#define WS_NR   41088      // nrpart[256][8]
#define WS_SEL  43136      // selpart[256]

// ---------------------------------------------------------------- kernel 0
// Zero colacc (8192) + the 66 sync counters (contiguous after colacc).
__global__ __launch_bounds__(1024) void k0(float* __restrict__ ws)
{
    const int idx = blockIdx.x * 1024 + threadIdx.x;
    if (idx < 8192 + 66) ws[WS_COL + idx] = 0.0f;
}

// ---------------------------------------------------------------- kernel main
// One resident kernel: 256 blocks x 512 threads = 1 block/CU (4x headroom,
// co-residency guaranteed -> in-kernel sync is deadlock-free).
// Phase 1 (rows 8b..8b+7): softmax -> P, lq2, D rowsum -> nnz/nr/sel partials.
//   Arrival: release fetch_add on cnt[b>>2] (4 producers per 32-row chunk).
// Phase 2 (col-tile b&3, row-chunk b>>2): waits ONLY on its own chunk counter
//   (its 3 neighbor blocks), then D*lq2 accumulation + colacc atomics.
// Finale: last-done block (acq_rel gate) computes the 97-float tail.
__global__ __launch_bounds__(512) void kmain(
    const float* __restrict__ W, const float* __restrict__ Dm,
    const float* __restrict__ g, float* __restrict__ out,
    float* __restrict__ ws)
{
    const int tid  = threadIdx.x;
    const int lane = tid & 63;
    const int w    = tid >> 6;              // wave 0..7
    const int b    = blockIdx.x;
    unsigned* cnt  = (unsigned*)ws + WS_CNT;

    // ================= phase 1: one row per wave =================
    {
        const int row = b * 8 + w;

        // softmax over the row's 64 logits
        float z = W[row * K + lane] + g[row * K + lane];
        float m = z;
        #pragma unroll
        for (int off = 32; off >= 1; off >>= 1)
            m = fmaxf(m, __shfl_xor(m, off, 64));
        float e = __expf(z - m);
        float s = e;
        #pragma unroll
        for (int off = 32; off >= 1; off >>= 1)
            s += __shfl_xor(s, off, 64);
        float p = e * __builtin_amdgcn_rcpf(s);
        out[OFF_P + row * K + lane] = p;

        // D rowsum (coalesced float4, whole wave on one 4KB row)
        const float4* Drow = (const float4*)(Dm + (size_t)row * C);
        float ds = 0.0f;
        #pragma unroll
        for (int j = 0; j < 4; ++j) {
            float4 v = Drow[lane + 64 * j];
            ds += (v.x + v.y) + (v.z + v.w);
        }
        #pragma unroll
        for (int off = 32; off >= 1; off >>= 1)
            ds += __shfl_xor(ds, off, 64);

        // per-channel (8-lane group) product of (1-p), sum of p
        float om = 1.0f - p, sc = p;
        #pragma unroll
        for (int off = 1; off <= 4; off <<= 1) {
            om *= __shfl_xor(om, off, 64);
            sc += __shfl_xor(sc, off, 64);
        }
        if ((lane & 7) == 0)   // clamp: q==0 -> -inf, then 0*-inf = NaN later
            ws[WS_LQ + row * CH + (lane >> 3)] =
                fmaxf(__builtin_amdgcn_logf(om), -1.0e30f);

        // row max for num_row_sel
        float pm = p;
        #pragma unroll
        for (int off = 32; off >= 1; off >>= 1)
            pm = fmaxf(pm, __shfl_xor(pm, off, 64));

        __shared__ float rn[8][64];
        __shared__ float rp[8][8];
        __shared__ float rsel[8];
        rn[w][lane] = p * ds;
        if ((lane & 7) == 0) rp[w][lane >> 3] = sc;
        if (lane == 0) rsel[w] = (pm > 0.99f) ? 1.0f : 0.0f;
        __syncthreads();   // drains all waves' lq2 stores too (vmcnt 0)

        // arrival for this block's 32-row chunk: lq2 rows are globally visible
        if (tid == 0)
            __hip_atomic_fetch_add(cnt + (b >> 2), 1u,
                __ATOMIC_RELEASE, __HIP_MEMORY_SCOPE_AGENT);

        if (tid < 64) {
            float v = rn[0][tid] + rn[1][tid] + rn[2][tid] + rn[3][tid]
                    + rn[4][tid] + rn[5][tid] + rn[6][tid] + rn[7][tid];
            ws[WS_NP + b * 64 + tid] = v;
        }
        if (tid < 8) {
            float v = 0.0f;
            #pragma unroll
            for (int ww = 0; ww < 8; ++ww) v += rp[ww][tid];
            ws[WS_NR + b * 8 + tid] = v;
        }
        if (tid == 0) {
            float v = 0.0f;
            #pragma unroll
            for (int ww = 0; ww < 8; ++ww) v += rsel[ww];
            ws[WS_SEL + b] = v;
        }
    }

    // ================= phase 2: colacc = D^T x lq2 =================
    {
        const int ct   = b & 3;
        const int rc   = b >> 2;
        const int c    = tid & 255;
        const int col  = ct * 256 + c;
        const int half = tid >> 8;           // wave-uniform (waves 0-3 / 4-7)

        // wait for the 4 producers of row-chunk rc (incl. self + 3 neighbors)
        if (tid == 0) {
            while (__hip_atomic_load(cnt + rc,
                       __ATOMIC_ACQUIRE, __HIP_MEMORY_SCOPE_AGENT) < 4u)
                __builtin_amdgcn_s_sleep(1);
        }
        __syncthreads();

        const int r0 = __builtin_amdgcn_readfirstlane(rc * 32 + half * 16);

        float l[8] = {0,0,0,0,0,0,0,0};
        #pragma unroll
        for (int i = 0; i < 16; ++i) {
            const int r = r0 + i;
            const float d = Dm[(size_t)r * C + col];
            const float* lr = ws + WS_LQ + r * CH;   // wave-uniform address
            #pragma unroll
            for (int j = 0; j < 8; ++j) l[j] += d * lr[j];
        }

        __shared__ float comb[8][256];
        if (half) {
            #pragma unroll
            for (int j = 0; j < 8; ++j) comb[j][c] = l[j];
        }
        __syncthreads();
        if (!half) {
            float* ca = ws + WS_COL;
            const int st = rc & 7;           // stagger ch order across rc
            #pragma unroll
            for (int jj = 0; jj < 8; ++jj) {
                const int j = (jj + st) & 7;
                atomicAdd(&ca[j * 1024 + col], l[j] + comb[j][c]);
            }
        }
        __syncthreads();   // drain this block's atomics (vmcnt 0)
    }

    // ---- completion gate: last finisher does the finale ----
    __shared__ int amLast;
    if (tid == 0) {
        __threadfence();
        unsigned old = __hip_atomic_fetch_add(cnt + 64, 1u,
            __ATOMIC_ACQ_REL, __HIP_MEMORY_SCOPE_AGENT);
        amLast = (old == 255u);   // acquire side invalidates stale L1/L2
    }
    __syncthreads();
    if (!amLast) return;

    // ================= finale (512 threads, one block) =================
    const int fl = tid & 63;
    const int fw = tid >> 6;    // 8 waves

    __shared__ float nc8[8];
    __shared__ float npr[8][64];
    __shared__ float nrr[8][8];
    __shared__ float selr[64];

    {   // num_col: wave fw owns channel fw; 16 cols per lane
        float ncl = 0.0f;
        #pragma unroll
        for (int j = 0; j < 16; ++j) {
            float sv = ws[WS_COL + fw * 1024 + j * 64 + fl];
            ncl += 1.0f - __builtin_amdgcn_exp2f(sv);
        }
        #pragma unroll
        for (int off = 32; off >= 1; off >>= 1)
            ncl += __shfl_xor(ncl, off, 64);
        if (fl == 0) nc8[fw] = ncl;
    }
    {   // nnz partials: wave fw sums its 32 phase-1 blocks for all 64 k
        float v = 0.0f;
        #pragma unroll
        for (int bb = 0; bb < 32; ++bb)
            v += ws[WS_NP + (fw * 32 + bb) * 64 + fl];
        npr[fw][fl] = v;
    }
    if (tid < 64) {   // nrow + sel partials
        const int ch2 = tid & 7, grp = tid >> 3;
        float v = 0.0f;
        #pragma unroll
        for (int bb = 0; bb < 32; ++bb)
            v += ws[WS_NR + (grp * 32 + bb) * CH + ch2];
        nrr[grp][ch2] = v;
        float sv = 0.0f;
        #pragma unroll
        for (int j = 0; j < 4; ++j)
            sv += ws[WS_SEL + j * 64 + tid];
        selr[tid] = sv;
    }
    __syncthreads();

    if (tid < 64) {
        float nnzv = 0.0f;
        #pragma unroll
        for (int g2 = 0; g2 < 8; ++g2) nnzv += npr[g2][tid];
        out[OFF_NNZ + tid] = nnzv;

        float sum = nnzv, mx = nnzv;
        #pragma unroll
        for (int off = 1; off <= 4; off <<= 1) {
            sum += __shfl_xor(sum, off, 64);
            mx = fmaxf(mx, __shfl_xor(mx, off, 64));
        }
        float sv = selr[tid];
        #pragma unroll
        for (int off = 32; off >= 1; off >>= 1)
            sv += __shfl_xor(sv, off, 64);
        if (tid == 0) out[OFF_SEL] = sv;

        if ((tid & 7) == 0) {
            const int chf = tid >> 3;
            float nr = 0.0f;
            #pragma unroll
            for (int g2 = 0; g2 < 8; ++g2) nr += nrr[g2][chf];
            const float nc = nc8[chf];
            out[OFF_TOT  + chf] = mx + nc + nr;
            out[OFF_MAX  + chf] = mx;
            out[OFF_NCOL + chf] = nc;
            out[OFF_NROW + chf] = nr;
            out[OFF_DEN  + chf] = sum / nr / nc;
        }
    }
}

extern "C" void kernel_launch(void* const* d_in, const int* in_sizes, int n_in,
                              void* d_out, int out_size, void* d_ws, size_t ws_size,
                              hipStream_t stream) {
    const float* W = (const float*)d_in[0];
    const float* D = (const float*)d_in[1];
    const float* g = (const float*)d_in[2];
    float* out = (float*)d_out;
    float* ws  = (float*)d_ws;

    k0<<<9, 1024, 0, stream>>>(ws);
    kmain<<<256, 512, 0, stream>>>(W, D, g, out, ws);
}

// Round 4
// 80.661 us; speedup vs baseline: 1.0981x; 1.0981x over previous
//
#include <hip/hip_runtime.h>
#include <math.h>

#define R 2048
#define C 1024
#define CH 8
#define K 64  // CH*BA

// Output layout (floats), reference return order:
#define OFF_P     0
#define OFF_TOT   (R*K)            // 131072
#define OFF_MAX   (OFF_TOT + 8)
#define OFF_NCOL  (OFF_MAX + 8)
#define OFF_NROW  (OFF_NCOL + 8)
#define OFF_NNZ   (OFF_NROW + 8)
#define OFF_DEN   (OFF_NNZ + 64)
#define OFF_SEL   (OFF_DEN + 8)

// ws layout (floats):
#define WS_LQ   0          // lq2[R][8]: clamped log2 of per-(row,ch) prod(1-p)
#define WS_COL  16384      // colacc[8][1024]: zeroed by k1, atomics from k2
#define WS_NP   24576      // nnzpart[256][64]
#define WS_NR   40960      // nrpart[256][8]
#define WS_SEL  43008      // selpart[256]
#define WS_CNT  43264      // completion counter (1 uint), zeroed by k1

// ---------------------------------------------------------------- kernel 1
// (verbatim from the 77.1us baseline) One row per wave. Softmax -> P, lq2,
// D rowsum -> nnz partial. Zeroes colacc + k2's completion counter.
__global__ __launch_bounds__(512) void k1(
    const float* __restrict__ W, const float* __restrict__ Dm,
    const float* __restrict__ g, float* __restrict__ P,
    float* __restrict__ ws)
{
    const int tid  = threadIdx.x;
    const int lane = tid & 63;
    const int w    = tid >> 6;              // wave 0..7
    const int row  = blockIdx.x * 8 + w;

    if (tid < 32) ws[WS_COL + blockIdx.x * 32 + tid] = 0.0f;
    if (blockIdx.x == 0 && tid == 32) ((unsigned*)ws)[WS_CNT] = 0u;

    // softmax over the row's 64 logits
    float z = W[row * K + lane] + g[row * K + lane];
    float m = z;
    #pragma unroll
    for (int off = 32; off >= 1; off >>= 1)
        m = fmaxf(m, __shfl_xor(m, off, 64));
    float e = __expf(z - m);
    float s = e;
    #pragma unroll
    for (int off = 32; off >= 1; off >>= 1)
        s += __shfl_xor(s, off, 64);
    float p = e * __builtin_amdgcn_rcpf(s);
    P[row * K + lane] = p;

    // D rowsum (coalesced float4, whole wave on one 4KB row)
    const float4* Drow = (const float4*)(Dm + (size_t)row * C);
    float ds = 0.0f;
    #pragma unroll
    for (int j = 0; j < 4; ++j) {
        float4 v = Drow[lane + 64 * j];
        ds += (v.x + v.y) + (v.z + v.w);
    }
    #pragma unroll
    for (int off = 32; off >= 1; off >>= 1)
        ds += __shfl_xor(ds, off, 64);

    // per-channel (8-lane group) product of (1-p), sum of p
    float om = 1.0f - p, sc = p;
    #pragma unroll
    for (int off = 1; off <= 4; off <<= 1) {
        om *= __shfl_xor(om, off, 64);
        sc += __shfl_xor(sc, off, 64);
    }
    if ((lane & 7) == 0)   // clamp: q==0 would give -inf, then 0*-inf = NaN in k2
        ws[WS_LQ + row * CH + (lane >> 3)] =
            fmaxf(__builtin_amdgcn_logf(om), -1.0e30f);

    // row max for num_row_sel
    float pm = p;
    #pragma unroll
    for (int off = 32; off >= 1; off >>= 1)
        pm = fmaxf(pm, __shfl_xor(pm, off, 64));

    // block-level combine (plain stores, no atomics)
    __shared__ float rn[8][64];
    __shared__ float rp[8][8];
    __shared__ float rsel[8];
    rn[w][lane] = p * ds;
    if ((lane & 7) == 0) rp[w][lane >> 3] = sc;
    if (lane == 0) rsel[w] = (pm > 0.99f) ? 1.0f : 0.0f;
    __syncthreads();

    if (tid < 64) {
        float v = rn[0][tid] + rn[1][tid] + rn[2][tid] + rn[3][tid]
                + rn[4][tid] + rn[5][tid] + rn[6][tid] + rn[7][tid];
        ws[WS_NP + blockIdx.x * 64 + tid] = v;
    }
    if (tid < 8) {
        float v = 0.0f;
        #pragma unroll
        for (int ww = 0; ww < 8; ++ww) v += rp[ww][tid];
        ws[WS_NR + blockIdx.x * 8 + tid] = v;
    }
    if (tid == 0) {
        float v = 0.0f;
        #pragma unroll
        for (int ww = 0; ww < 8; ++ww) v += rsel[ww];
        ws[WS_SEL + blockIdx.x] = v;
    }
}

// ---------------------------------------------------------------- kernel 2
// NEW geometry: 256 blocks = 16 col-tiles(64 cols) x 16 row-chunks(128 rows),
// 512 threads = 8 waves (2 waves/SIMD for latency hiding; was 1). Wave w owns
// 16 rows x 64 cols: coalesced 256B D loads + wave-uniform s_load lq2 rows.
// LDS-combine the 8 wave-partials -> ONE atomic per thread (131K total,
// was 524K; 256 colliding updates/line, was 1024). Last-done block (proven
// r1 gate) runs the finale.
__global__ __launch_bounds__(512) void k2(
    const float* __restrict__ Dm, float* __restrict__ ws,
    float* __restrict__ out)
{
    const int tid  = threadIdx.x;
    const int lane = tid & 63;
    const int w    = tid >> 6;              // wave 0..7
    const int ct   = blockIdx.x & 15;
    const int rc   = blockIdx.x >> 4;
    const int col  = ct * 64 + lane;

    // wave-uniform row base -> lq2 rows become scalar s_loads
    const int r0 = __builtin_amdgcn_readfirstlane(rc * 128 + w * 16);

    float l[8] = {0,0,0,0,0,0,0,0};
    #pragma unroll
    for (int i = 0; i < 16; ++i) {
        const int r = r0 + i;
        const float d = Dm[(size_t)r * C + col];
        const float* lr = ws + WS_LQ + r * CH;   // wave-uniform address
        #pragma unroll
        for (int j = 0; j < 8; ++j) l[j] += d * lr[j];
    }

    __shared__ float comb[8][8][64];   // [wave][ch][col-lane], 16 KB
    #pragma unroll
    for (int j = 0; j < 8; ++j) comb[w][j][lane] = l[j];
    __syncthreads();

    {   // thread (ch = w, ln = lane) folds 8 wave-partials -> 1 atomic
        float v = 0.0f;
        #pragma unroll
        for (int ww = 0; ww < 8; ++ww) v += comb[ww][w][lane];
        atomicAdd(&ws[WS_COL + w * 1024 + ct * 64 + lane], v);
    }
    // drain this block's atomics (syncthreads emits s_waitcnt vmcnt(0))
    __syncthreads();

    // ---- completion gate: last finisher does the finale ----
    __shared__ int amLast;
    if (tid == 0) {
        unsigned old = __hip_atomic_fetch_add(
            (unsigned*)ws + WS_CNT, 1u,
            __ATOMIC_ACQ_REL, __HIP_MEMORY_SCOPE_AGENT);
        amLast = (old == 255u);   // acquire side invalidates stale L1/L2
    }
    __syncthreads();
    if (!amLast) return;

    // ---------------- finale (512 threads, one block) ----------------
    const int fl = tid & 63;
    const int fw = tid >> 6;    // 8 waves

    __shared__ float nc8[8];
    __shared__ float npr[8][64];
    __shared__ float nrr[8][8];
    __shared__ float selr[64];

    {   // num_col: wave fw owns channel fw; 16 cols per lane
        float ncl = 0.0f;
        #pragma unroll
        for (int j = 0; j < 16; ++j) {
            float sv = ws[WS_COL + fw * 1024 + j * 64 + fl];
            ncl += 1.0f - __builtin_amdgcn_exp2f(sv);
        }
        #pragma unroll
        for (int off = 32; off >= 1; off >>= 1)
            ncl += __shfl_xor(ncl, off, 64);
        if (fl == 0) nc8[fw] = ncl;
    }
    {   // nnz partials: wave fw sums its 32 k1-blocks for all 64 k
        float v = 0.0f;
        #pragma unroll
        for (int b = 0; b < 32; ++b)
            v += ws[WS_NP + (fw * 32 + b) * 64 + fl];
        npr[fw][fl] = v;
    }
    if (tid < 64) {   // nrow + sel partials
        const int ch2 = tid & 7, grp = tid >> 3;
        float v = 0.0f;
        #pragma unroll
        for (int b = 0; b < 32; ++b)
            v += ws[WS_NR + (grp * 32 + b) * CH + ch2];
        nrr[grp][ch2] = v;
        float sv = 0.0f;
        #pragma unroll
        for (int j = 0; j < 4; ++j)
            sv += ws[WS_SEL + j * 64 + tid];
        selr[tid] = sv;
    }
    __syncthreads();

    if (tid < 64) {
        float nnzv = 0.0f;
        #pragma unroll
        for (int g2 = 0; g2 < 8; ++g2) nnzv += npr[g2][tid];
        out[OFF_NNZ + tid] = nnzv;

        float sum = nnzv, mx = nnzv;
        #pragma unroll
        for (int off = 1; off <= 4; off <<= 1) {
            sum += __shfl_xor(sum, off, 64);
            mx = fmaxf(mx, __shfl_xor(mx, off, 64));
        }
        float sv = selr[tid];
        #pragma unroll
        for (int off = 32; off >= 1; off >>= 1)
            sv += __shfl_xor(sv, off, 64);
        if (tid == 0) out[OFF_SEL] = sv;

        if ((tid & 7) == 0) {
            const int ch = tid >> 3;
            float nr = 0.0f;
            #pragma unroll
            for (int g2 = 0; g2 < 8; ++g2) nr += nrr[g2][ch];
            const float nc = nc8[ch];
            out[OFF_TOT  + ch] = mx + nc + nr;
            out[OFF_MAX  + ch] = mx;
            out[OFF_NCOL + ch] = nc;
            out[OFF_NROW + ch] = nr;
            out[OFF_DEN  + ch] = sum / nr / nc;
        }
    }
}

extern "C" void kernel_launch(void* const* d_in, const int* in_sizes, int n_in,
                              void* d_out, int out_size, void* d_ws, size_t ws_size,
                              hipStream_t stream) {
    const float* W = (const float*)d_in[0];
    const float* D = (const float*)d_in[1];
    const float* g = (const float*)d_in[2];
    float* out = (float*)d_out;
    float* ws  = (float*)d_ws;

    k1<<<256, 512, 0, stream>>>(W, D, g, out, ws);
    k2<<<256, 512, 0, stream>>>(D, ws, out);
}

// Round 5
// 76.072 us; speedup vs baseline: 1.1643x; 1.0603x over previous
//
#include <hip/hip_runtime.h>
#include <math.h>

#define R 2048
#define C 1024
#define CH 8
#define K 64  // CH*BA

// Output layout (floats), reference return order:
#define OFF_P     0
#define OFF_TOT   (R*K)            // 131072
#define OFF_MAX   (OFF_TOT + 8)
#define OFF_NCOL  (OFF_MAX + 8)
#define OFF_NROW  (OFF_NCOL + 8)
#define OFF_NNZ   (OFF_NROW + 8)
#define OFF_DEN   (OFF_NNZ + 64)
#define OFF_SEL   (OFF_DEN + 8)

// ws layout (floats):
#define WS_LQ   0          // lq2[R][8]: clamped log2 of per-(row,ch) prod(1-p)
#define WS_COL  16384      // colacc[8][1024]: zeroed by k1, atomics from k2
#define WS_NP   24576      // nnzpart[256][64]
#define WS_NR   40960      // nrpart[256][8]
#define WS_SEL  43008      // selpart[256]

// ---------------------------------------------------------------- kernel 1
// One row per wave (2048 waves). Softmax -> P, lq2, D rowsum -> nnz partial.
// Also zeroes colacc for k2's atomics (k2 starts only after k1 retires).
__global__ __launch_bounds__(512) void k1(
    const float* __restrict__ W, const float* __restrict__ Dm,
    const float* __restrict__ g, float* __restrict__ P,
    float* __restrict__ ws)
{
    const int tid  = threadIdx.x;
    const int lane = tid & 63;
    const int w    = tid >> 6;              // wave 0..7
    const int row  = blockIdx.x * 8 + w;

    if (tid < 32) ws[WS_COL + blockIdx.x * 32 + tid] = 0.0f;

    // softmax over the row's 64 logits
    float z = W[row * K + lane] + g[row * K + lane];
    float m = z;
    #pragma unroll
    for (int off = 32; off >= 1; off >>= 1)
        m = fmaxf(m, __shfl_xor(m, off, 64));
    float e = __expf(z - m);
    float s = e;
    #pragma unroll
    for (int off = 32; off >= 1; off >>= 1)
        s += __shfl_xor(s, off, 64);
    float p = e * __builtin_amdgcn_rcpf(s);
    P[row * K + lane] = p;

    // D rowsum (coalesced float4, whole wave on one 4KB row)
    const float4* Drow = (const float4*)(Dm + (size_t)row * C);
    float ds = 0.0f;
    #pragma unroll
    for (int j = 0; j < 4; ++j) {
        float4 v = Drow[lane + 64 * j];
        ds += (v.x + v.y) + (v.z + v.w);
    }
    #pragma unroll
    for (int off = 32; off >= 1; off >>= 1)
        ds += __shfl_xor(ds, off, 64);

    // per-channel (8-lane group) product of (1-p), sum of p
    float om = 1.0f - p, sc = p;
    #pragma unroll
    for (int off = 1; off <= 4; off <<= 1) {
        om *= __shfl_xor(om, off, 64);
        sc += __shfl_xor(sc, off, 64);
    }
    if ((lane & 7) == 0)   // clamp: q==0 would give -inf, then 0*-inf = NaN in k2
        ws[WS_LQ + row * CH + (lane >> 3)] =
            fmaxf(__builtin_amdgcn_logf(om), -1.0e30f);

    // row max for num_row_sel
    float pm = p;
    #pragma unroll
    for (int off = 32; off >= 1; off >>= 1)
        pm = fmaxf(pm, __shfl_xor(pm, off, 64));

    // block-level combine (plain stores, no atomics)
    __shared__ float rn[8][64];
    __shared__ float rp[8][8];
    __shared__ float rsel[8];
    rn[w][lane] = p * ds;
    if ((lane & 7) == 0) rp[w][lane >> 3] = sc;
    if (lane == 0) rsel[w] = (pm > 0.99f) ? 1.0f : 0.0f;
    __syncthreads();

    if (tid < 64) {
        float v = rn[0][tid] + rn[1][tid] + rn[2][tid] + rn[3][tid]
                + rn[4][tid] + rn[5][tid] + rn[6][tid] + rn[7][tid];
        ws[WS_NP + blockIdx.x * 64 + tid] = v;
    }
    if (tid < 8) {
        float v = 0.0f;
        #pragma unroll
        for (int ww = 0; ww < 8; ++ww) v += rp[ww][tid];
        ws[WS_NR + blockIdx.x * 8 + tid] = v;
    }
    if (tid == 0) {
        float v = 0.0f;
        #pragma unroll
        for (int ww = 0; ww < 8; ++ww) v += rsel[ww];
        ws[WS_SEL + blockIdx.x] = v;
    }
}

// ---------------------------------------------------------------- kernel 2
// 256 blocks = 4 col-tiles(256) x 64 row-chunks(32). Hot loop: 1 coalesced D
// load + 1 wave-uniform lq2 row (scalarized s_load) + 8 fmac. 8 atomics/thread.
__global__ __launch_bounds__(256) void k2(
    const float* __restrict__ Dm, float* __restrict__ ws)
{
    const int tid = threadIdx.x;
    const int ct  = blockIdx.x & 3;
    const int rc  = blockIdx.x >> 2;
    const int col = ct * 256 + tid;

    float l0=0,l1=0,l2=0,l3=0,l4=0,l5=0,l6=0,l7=0;
    const int r0 = rc * 32;
    #pragma unroll 4
    for (int i = 0; i < 32; ++i) {
        const int r = r0 + i;
        float d = Dm[(size_t)r * C + col];
        const float* lr = ws + WS_LQ + r * CH;   // wave-uniform address
        l0 += d * lr[0]; l1 += d * lr[1]; l2 += d * lr[2]; l3 += d * lr[3];
        l4 += d * lr[4]; l5 += d * lr[5]; l6 += d * lr[6]; l7 += d * lr[7];
    }
    float* ca = ws + WS_COL;
    atomicAdd(&ca[0 * 1024 + col], l0);
    atomicAdd(&ca[1 * 1024 + col], l1);
    atomicAdd(&ca[2 * 1024 + col], l2);
    atomicAdd(&ca[3 * 1024 + col], l3);
    atomicAdd(&ca[4 * 1024 + col], l4);
    atomicAdd(&ca[5 * 1024 + col], l5);
    atomicAdd(&ca[6 * 1024 + col], l6);
    atomicAdd(&ca[7 * 1024 + col], l7);
}

// ---------------------------------------------------------------- kernel 3
// Single block: colacc -> num_col, partial reductions, 97-float tail.
__global__ __launch_bounds__(1024) void k3(const float* __restrict__ ws,
                                           float* __restrict__ out)
{
    const int tid = threadIdx.x;
    __shared__ float red[1024];
    __shared__ float npr[16][64];
    __shared__ float nrr[8][8];
    __shared__ float selr[64];
    __shared__ float nc8[8];

    {   // num_col: 1 - 2^colacc, per-ch partial over 8 cols each
        const int ch = tid >> 7, c0 = tid & 127;
        float ncl = 0.0f;
        #pragma unroll
        for (int j = 0; j < 8; ++j)
            ncl += 1.0f - __builtin_amdgcn_exp2f(
                              ws[WS_COL + ch * 1024 + j * 128 + c0]);
        red[tid] = ncl;
    }
    {   // nnz partials: 16 groups x 16 blocks each
        const int l = tid & 63, grp = tid >> 6;
        float v = 0.0f;
        #pragma unroll
        for (int b = 0; b < 16; ++b)
            v += ws[WS_NP + (grp * 16 + b) * 64 + l];
        npr[grp][l] = v;
    }
    if (tid < 64) {
        const int ch = tid & 7, grp = tid >> 3;
        float v = 0.0f;
        #pragma unroll
        for (int b = 0; b < 32; ++b)
            v += ws[WS_NR + (grp * 32 + b) * CH + ch];
        nrr[grp][ch] = v;
        float sv = 0.0f;
        #pragma unroll
        for (int j = 0; j < 4; ++j)
            sv += ws[WS_SEL + j * 64 + tid];
        selr[tid] = sv;
    }
    __syncthreads();

    // reduce num_col within each per-ch 128-thread group
    #pragma unroll
    for (int off = 64; off >= 1; off >>= 1) {
        if ((tid & 127) < off) red[tid] += red[tid + off];
        __syncthreads();
    }
    if ((tid & 127) == 0) nc8[tid >> 7] = red[tid];
    __syncthreads();

    if (tid < 64) {
        float nnzv = 0.0f;
        #pragma unroll
        for (int g2 = 0; g2 < 16; ++g2) nnzv += npr[g2][tid];
        out[OFF_NNZ + tid] = nnzv;

        float sum = nnzv, mx = nnzv;
        #pragma unroll
        for (int off = 1; off <= 4; off <<= 1) {
            sum += __shfl_xor(sum, off, 64);
            mx = fmaxf(mx, __shfl_xor(mx, off, 64));
        }
        float sv = selr[tid];
        #pragma unroll
        for (int off = 32; off >= 1; off >>= 1)
            sv += __shfl_xor(sv, off, 64);
        if (tid == 0) out[OFF_SEL] = sv;

        if ((tid & 7) == 0) {
            const int ch = tid >> 3;
            float nr = 0.0f;
            #pragma unroll
            for (int g2 = 0; g2 < 8; ++g2) nr += nrr[g2][ch];
            const float nc = nc8[ch];
            out[OFF_TOT  + ch] = mx + nc + nr;
            out[OFF_MAX  + ch] = mx;
            out[OFF_NCOL + ch] = nc;
            out[OFF_NROW + ch] = nr;
            out[OFF_DEN  + ch] = sum / nr / nc;
        }
    }
}

extern "C" void kernel_launch(void* const* d_in, const int* in_sizes, int n_in,
                              void* d_out, int out_size, void* d_ws, size_t ws_size,
                              hipStream_t stream) {
    const float* W = (const float*)d_in[0];
    const float* D = (const float*)d_in[1];
    const float* g = (const float*)d_in[2];
    float* out = (float*)d_out;
    float* ws  = (float*)d_ws;

    k1<<<256, 512, 0, stream>>>(W, D, g, out, ws);
    k2<<<256, 256, 0, stream>>>(D, ws);
    k3<<<1,  1024, 0, stream>>>(ws, out);
}